// Round 5
// baseline (42184.769 us; speedup 1.0000x reference)
//
#include <hip/hip_runtime.h>

// RepetHead: 4 layers of (3x3 offset conv -> DCNv1 deform conv -> ReLU)
// B=4, C=256, H=W=64, K=9 taps.
// Round 5: activations live ONLY as bf16-hi transposed planes xT[b][pos][c]
// (ping-pong in ws). Deform = fused bilinear + bf16 MFMA, products
// (a_hi + a_lo)*b_hi where a_hi/a_lo split the fp32 bilinear sample.
// M=64 x N=128 blocks (4x less B L2 traffic than r4), hi-only B (2x less),
// software-pipelined K-loop (double-buffered sA, 1 barrier/chunk, G/B
// prefetch issued after the barrier to overlap MFMA).
//
// ws layout (floats):
//   offs :   294,912
//   wph  : 1,179,648  (2,359,296 ushort, deform B frag-packed, bf16-hi)
//   owph :   147,456  (  294,912 ushort, offset-conv B frag-packed)
//   xTA  : 2,097,152  (4,194,304 ushort, plane ping)
//   xTB  : 2,097,152  (4,194,304 ushort, plane pong)
// total 5,816,320 floats = 23.3 MB

#define HW 4096

typedef __attribute__((ext_vector_type(8))) __bf16 bf16x8;
typedef __attribute__((ext_vector_type(4))) float f32x4;
typedef __attribute__((ext_vector_type(8))) unsigned short u16x8;

__device__ inline unsigned int f2bf_bits(float f) {
  unsigned int u = __float_as_uint(f);
  return (u + 0x7fffu + ((u >> 16) & 1u)) >> 16;   // RNE to bf16
}
__device__ inline float bf_hi_f(unsigned short h) {
  return __uint_as_float(((unsigned int)h) << 16);
}

// ---------------------------------------------------------------------------
// w[r][o][c][ky][kx] -> frag-packed wph[r][q=72][nt=16][lane=64][j=8] (bf16-hi)
// n = nt*16+(lane&15); kk = q*32+(lane>>4)*8+j; c = kk&255; k = kk>>8.
__global__ __launch_bounds__(256) void wpack_kernel(
    const float* __restrict__ w, unsigned short* __restrict__ wph) {
  const int f = blockIdx.x * 256 + threadIdx.x;   // < 2,359,296
  const int j  = f & 7;
  const int l  = (f >> 3) & 63;
  const int nt = (f >> 9) & 15;
  const int q  = (f >> 13) % 72;
  const int r  = f / 589824;
  const int n  = nt * 16 + (l & 15);
  const int kk = q * 32 + ((l >> 4) << 3) + j;
  const int c  = kk & 255, k = kk >> 8;
  wph[f] = (unsigned short)f2bf_bits(w[((r * 256 + n) * 256 + c) * 9 + k]);
}

// offw[r][18][256][3][3] -> owph[r][q=72][nt=2][lane=64][j=8] (n>=18 -> 0)
__global__ __launch_bounds__(256) void offwpack_kernel(
    const float* __restrict__ offw, unsigned short* __restrict__ owph) {
  const int f = blockIdx.x * 256 + threadIdx.x;   // < 294,912
  const int j  = f & 7;
  const int l  = (f >> 3) & 63;
  const int nt = (f >> 9) & 1;
  const int q  = (f >> 10) % 72;
  const int r  = f / 73728;
  const int n  = nt * 16 + (l & 15);
  const int kk = q * 32 + ((l >> 4) << 3) + j;
  const int c  = kk & 255, k = kk >> 8;
  const float v = (n < 18) ? offw[((r * 18 + n) * 256 + c) * 9 + k] : 0.f;
  owph[f] = (unsigned short)f2bf_bits(v);
}

// ---------------------------------------------------------------------------
// x [4][256][4096] fp32 -> xT [4][4096][256] bf16-hi (transpose + cast)
__global__ __launch_bounds__(256) void xpose_kernel(
    const float* __restrict__ x, unsigned short* __restrict__ xh) {
  const int p0 = blockIdx.x * 64;     // pos tile
  const int c0 = blockIdx.y * 64;     // channel tile
  const int b  = blockIdx.z;
  __shared__ float sT[64][65];
  const int t = threadIdx.x;
  const int pj = t & 63, ci0 = (t >> 6) * 16;
  const float* __restrict__ xb = x + ((size_t)(b * 256 + c0)) * HW + p0;
#pragma unroll
  for (int u = 0; u < 16; ++u)
    sT[ci0 + u][pj] = xb[(size_t)(ci0 + u) * HW + pj];
  __syncthreads();
  const int pr = t >> 2, cs = (t & 3) * 16;
  u16x8 va, vb;
#pragma unroll
  for (int u = 0; u < 8; ++u) va[u] = (unsigned short)f2bf_bits(sT[cs + u][pr]);
#pragma unroll
  for (int u = 0; u < 8; ++u) vb[u] = (unsigned short)f2bf_bits(sT[cs + 8 + u][pr]);
  const size_t o = ((size_t)b * HW + p0 + pr) * 256 + c0 + cs;
  *(u16x8*)(xh + o) = va;
  *(u16x8*)(xh + o + 8) = vb;
}

// ---------------------------------------------------------------------------
// Offset conv, zero-LDS MFMA (r4-proven). block = 32m x 32n, 4 waves.
__global__ __launch_bounds__(256) void offconv_mfma(
    const unsigned short* __restrict__ xh,
    const unsigned short* __restrict__ owh,
    const float* __restrict__ bias, float* __restrict__ offs) {
  const int gid = blockIdx.x;                 // 0..511
  const int b = (gid & 7) >> 1;
  const int idx = ((gid >> 3) << 1) | (gid & 1);   // 0..127
  const int h = idx >> 1, w0 = (idx & 1) << 5;
  const int t = threadIdx.x, lane = t & 63, wv = t >> 6;
  const int frow = lane & 15, fgrp = lane >> 4;
  const int mt = wv & 1, nt = wv >> 1;
  const int m = w0 + mt * 16 + frow;          // w coordinate of A row

  f32x4 acc = {0.f, 0.f, 0.f, 0.f};
  const u16x8 z8 = {};
  const size_t xb = (size_t)b * HW;

  for (int k = 0; k < 9; ++k) {
    const int ky = k / 3 - 1, kx = k % 3 - 1;
    if ((unsigned)(h + ky) >= 64u) continue;  // block-uniform: tap row is 0
    const bool vpx = (unsigned)(m + kx) < 64u;
    const int cpx = (m + kx) < 0 ? 0 : ((m + kx) > 63 ? 63 : (m + kx));
    const size_t abase = (xb + (size_t)((h + ky) * 64 + cpx)) * 256 + fgrp * 8;
#pragma unroll
    for (int cc = 0; cc < 8; ++cc) {
      const int q = k * 8 + cc;
      u16x8 ahr = *(const u16x8*)(xh + abase + cc * 32);
      if (!vpx) ahr = z8;
      const u16x8 bhr = ((const u16x8*)owh)[(q * 2 + nt) * 64 + lane];
      const bf16x8 ah = __builtin_bit_cast(bf16x8, ahr);
      const bf16x8 bh = __builtin_bit_cast(bf16x8, bhr);
      acc = __builtin_amdgcn_mfma_f32_16x16x32_bf16(ah, bh, acc, 0, 0, 0);
    }
  }
  const int oc = nt * 16 + frow;              // C/D: col = lane&15 -> n
  if (oc < 18) {
    const float bv = bias[oc];
    const int wbase = w0 + mt * 16 + fgrp * 4;  // C/D: row = (lane>>4)*4 + r
    float* __restrict__ op = offs + (size_t)(b * 18 + oc) * HW + h * 64 + wbase;
#pragma unroll
    for (int r = 0; r < 4; ++r) op[r] = acc[r] + bv;
  }
}

// ---------------------------------------------------------------------------
// Fused bilinear-sample + bf16 MFMA GEMM + ReLU, software-pipelined.
// Block: M=64 (full row h), N=128 (half of channels, nh). 4 waves as
// 2m-groups x 2n-groups; per wave 2 m-tiles x 4 n-tiles x 2 products.
__global__ __launch_bounds__(256) void deform_mfma(
    const unsigned short* __restrict__ xh,   // [4][4096][256] bf16-hi plane
    const float* __restrict__ offs,          // [4][18][4096]
    const unsigned short* __restrict__ wph,  // [72][16][64][8] this layer
    unsigned short* __restrict__ yth,        // next plane (layers 0-2)
    float* __restrict__ outf) {              // fp32 NCHW out (layer 3)
  const int gid = blockIdx.x;                  // 0..511
  const int b = (gid & 7) >> 1;                // 2 XCDs per batch image
  const int rh = ((gid >> 3) << 1) | (gid & 1);   // 0..127
  const int h = rh >> 1, nh = rh & 1;
  const int t = threadIdx.x, lane = t & 63, wv = t >> 6;
  const int mw = wv & 1, nw = wv >> 1;
  const int frow = lane & 15, quad = lane >> 4;
  const int sm = t & 63, cg = t >> 6;          // staging: m, channel group

  __shared__ __align__(16) unsigned char s_mem[18432];
  float* s_cw = (float*)s_mem;                 // [9][4][64]
  int*   s_ci = (int*)(s_mem + 9216);          // [9][4][64]
  __shared__ __align__(16) unsigned short sA[2][2][64][40];  // [buf][hi/lo][m][k]

  // phase 0: per (k, m) bilinear setup, m = w coordinate (full row)
  for (int i = t; i < 576; i += 256) {
    const int k = i >> 6, m = i & 63;
    const int ky = k / 3 - 1, kx = k % 3 - 1;
    const int pos = h * 64 + m;
    const float dy = offs[(b * 18 + 2 * k) * HW + pos];
    const float dx = offs[(b * 18 + 2 * k + 1) * HW + pos];
    const float py = (float)(h + ky) + dy;
    const float px = (float)(m + kx) + dx;
    const float y0f = floorf(py), x0f = floorf(px);
    const float wy = py - y0f, wx = px - x0f;
    const int y0 = (int)y0f, x0 = (int)x0f;
#pragma unroll
    for (int j = 0; j < 4; ++j) {
      const int yi = y0 + (j >> 1), xi = x0 + (j & 1);
      const bool v = (yi >= 0) && (yi < 64) && (xi >= 0) && (xi < 64);
      const float wgt = ((j >> 1) ? wy : 1.f - wy) * ((j & 1) ? wx : 1.f - wx);
      s_cw[(k * 4 + j) * 64 + m] = v ? wgt : 0.f;
      const int yc = yi < 0 ? 0 : (yi > 63 ? 63 : yi);
      const int xc = xi < 0 ? 0 : (xi > 63 ? 63 : xi);
      s_ci[(k * 4 + j) * 64 + m] = yc * 64 + xc;
    }
  }
  __syncthreads();

  f32x4 acc[2][4];
#pragma unroll
  for (int mt = 0; mt < 2; ++mt)
#pragma unroll
    for (int nt = 0; nt < 4; ++nt) acc[mt][nt] = (f32x4){0.f, 0.f, 0.f, 0.f};

  const unsigned short* __restrict__ xbh = xh + (size_t)b * HW * 256;
  const u16x8* __restrict__ wp = (const u16x8*)wph;

  u16x8 G[2][4], B[2][4];
  float cwr[4]; int cir[4];
#pragma unroll
  for (int j = 0; j < 4; ++j) {   // k = 0 staging params
    cwr[j] = s_cw[j * 64 + sm];
    cir[j] = s_ci[j * 64 + sm];
  }
#pragma unroll
  for (int j = 0; j < 4; ++j)     // chunk 0 gather (c0 = cg*8)
    G[0][j] = *(const u16x8*)(xbh + (size_t)cir[j] * 256 + cg * 8);
#pragma unroll
  for (int i = 0; i < 4; ++i)     // chunk 0 B frags
    B[0][i] = wp[(nh * 8 + nw * 4 + i) * 64 + lane];

  int buf = 0;
#pragma unroll 2
  for (int cc = 0; cc < 72; ++cc) {
    const int cur = cc & 1, nxt = cur ^ 1;
    // bilinear combine (fp32) from prefetched corners
    float v[8];
#pragma unroll
    for (int u = 0; u < 8; ++u) {
      float s = cwr[0] * bf_hi_f(G[cur][0][u]);
      s = fmaf(cwr[1], bf_hi_f(G[cur][1][u]), s);
      s = fmaf(cwr[2], bf_hi_f(G[cur][2][u]), s);
      v[u] = fmaf(cwr[3], bf_hi_f(G[cur][3][u]), s);
    }
    u16x8 hv, lv;
#pragma unroll
    for (int u = 0; u < 8; ++u) {
      const unsigned int hb = f2bf_bits(v[u]);
      hv[u] = (unsigned short)hb;
      lv[u] = (unsigned short)f2bf_bits(v[u] - __uint_as_float(hb << 16));
    }
    *(u16x8*)&sA[buf][0][sm][cg * 8] = hv;
    *(u16x8*)&sA[buf][1][sm][cg * 8] = lv;
    __syncthreads();   // sA[buf] visible; prev buf reads already drained
    // prefetch chunk cc+1 AFTER the barrier -> loads overlap MFMA below
    if (cc < 71) {
      const int cn = cc + 1;
      if ((cn & 7) == 0) {
        const int k = cn >> 3;
#pragma unroll
        for (int j = 0; j < 4; ++j) {
          cwr[j] = s_cw[(k * 4 + j) * 64 + sm];
          cir[j] = s_ci[(k * 4 + j) * 64 + sm];
        }
      }
      const int c0 = (cn & 7) * 32 + cg * 8;
#pragma unroll
      for (int j = 0; j < 4; ++j)
        G[nxt][j] = *(const u16x8*)(xbh + (size_t)cir[j] * 256 + c0);
#pragma unroll
      for (int i = 0; i < 4; ++i)
        B[nxt][i] = wp[((size_t)cn * 16 + nh * 8 + nw * 4 + i) * 64 + lane];
    }
    // A frags + MFMA: (a_hi + a_lo) * b_hi
    bf16x8 ah[2], al[2];
#pragma unroll
    for (int mt = 0; mt < 2; ++mt) {
      const int row = (mw * 2 + mt) * 16 + frow;
      ah[mt] = __builtin_bit_cast(bf16x8, *(const u16x8*)&sA[buf][0][row][quad * 8]);
      al[mt] = __builtin_bit_cast(bf16x8, *(const u16x8*)&sA[buf][1][row][quad * 8]);
    }
#pragma unroll
    for (int nt = 0; nt < 4; ++nt) {
      const bf16x8 bv = __builtin_bit_cast(bf16x8, B[cur][nt]);
#pragma unroll
      for (int mt = 0; mt < 2; ++mt) {
        acc[mt][nt] = __builtin_amdgcn_mfma_f32_16x16x32_bf16(ah[mt], bv, acc[mt][nt], 0, 0, 0);
        acc[mt][nt] = __builtin_amdgcn_mfma_f32_16x16x32_bf16(al[mt], bv, acc[mt][nt], 0, 0, 0);
      }
    }
    buf ^= 1;
  }

  if (outf) {
    // final layer: ReLU + direct fp32 NCHW scatter (float4 per tile-row)
#pragma unroll
    for (int mt = 0; mt < 2; ++mt)
#pragma unroll
      for (int nt = 0; nt < 4; ++nt) {
        const int n = nh * 128 + (nw * 4 + nt) * 16 + frow;
        const int pos = h * 64 + (mw * 2 + mt) * 16 + quad * 4;
        float4 vv;
        vv.x = fmaxf(acc[mt][nt][0], 0.f);
        vv.y = fmaxf(acc[mt][nt][1], 0.f);
        vv.z = fmaxf(acc[mt][nt][2], 0.f);
        vv.w = fmaxf(acc[mt][nt][3], 0.f);
        *(float4*)&outf[(size_t)(b * 256 + n) * HW + pos] = vv;
      }
  } else {
    // layers 0-2: ReLU + bf16-hi transposed plane via per-wave LDS slice
    __syncthreads();   // all K-loop s_mem/sA traffic done before union reuse
    unsigned short* sW = (unsigned short*)s_mem + wv * 2048;  // [32][64]
#pragma unroll
    for (int mt = 0; mt < 2; ++mt)
#pragma unroll
      for (int nt = 0; nt < 4; ++nt)
#pragma unroll
        for (int r = 0; r < 4; ++r)
          sW[(mt * 16 + quad * 4 + r) * 64 + nt * 16 + frow] =
              (unsigned short)f2bf_bits(fmaxf(acc[mt][nt][r], 0.f));
    __syncthreads();
    const int lm = lane & 31, cg2 = lane >> 5;
    const int pos = h * 64 + mw * 32 + lm;
    unsigned short* __restrict__ yp =
        yth + ((size_t)b * HW + pos) * 256 + nh * 128 + nw * 64 + cg2 * 32;
#pragma unroll
    for (int g = 0; g < 4; ++g)
      *(u16x8*)(yp + g * 8) = *(const u16x8*)&sW[lm * 64 + cg2 * 32 + g * 8];
  }
}

extern "C" void kernel_launch(void* const* d_in, const int* in_sizes, int n_in,
                              void* d_out, int out_size, void* d_ws, size_t ws_size,
                              hipStream_t stream) {
  const float* x0   = (const float*)d_in[0];  // [4][256][64][64]
  const float* offw = (const float*)d_in[1];  // [4][18][256][3][3]
  const float* offb = (const float*)d_in[2];  // [4][18]
  const float* w    = (const float*)d_in[3];  // [4][256][256][3][3]
  float* out = (float*)d_out;                 // [4][256][64][64]
  float* ws  = (float*)d_ws;

  float* offs = ws;                                     //   294,912 floats
  unsigned short* wph  = (unsigned short*)(ws + 294912);    // 2,359,296 ushort
  unsigned short* owph = wph + 2359296;                     //   294,912 ushort
  unsigned short* xTA  = owph + 294912;                     // 4,194,304 ushort
  unsigned short* xTB  = xTA + 4194304;                     // 4,194,304 ushort

  wpack_kernel<<<9216, 256, 0, stream>>>(w, wph);
  offwpack_kernel<<<1152, 256, 0, stream>>>(offw, owph);
  xpose_kernel<<<dim3(64, 4, 4), 256, 0, stream>>>(x0, xTA);

  unsigned short* pin = xTA;
  unsigned short* pout = xTB;
  for (int r = 0; r < 4; ++r) {
    offconv_mfma<<<512, 256, 0, stream>>>(pin, owph + r * 73728,
                                          offb + r * 18, offs);
    deform_mfma<<<512, 256, 0, stream>>>(pin, offs,
                                         wph + (size_t)r * 589824,
                                         (r < 3) ? pout : nullptr,
                                         (r < 3) ? nullptr : out);
    unsigned short* tmp = pin; pin = pout; pout = tmp;
  }
}

// Round 6
// 500.343 us; speedup vs baseline: 84.3117x; 84.3117x over previous
//
#include <hip/hip_runtime.h>

// RepetHead: 4 layers of (3x3 offset conv -> DCNv1 deform conv -> ReLU)
// B=4, C=256, H=W=64, K=9 taps.
// Round 6: identical design to round 5 (bf16-hi transposed activation
// planes, M=64 x N=128 deform blocks, hi-only B, (a_hi+a_lo)*b_hi MFMA,
// double-buffered sA with 1 barrier/chunk and post-barrier prefetch) BUT
// the K-loop is manually written as 36 x 2 chunk-bodies with LITERAL
// buffer indices: r5's runtime-indexed register arrays (G[cur]) compiled
// to scratch/select storms (42 ms, VALUBusy 39%, MfmaUtil 0.1%).
//
// ws layout (floats):
//   offs :   294,912
//   wph  : 1,179,648  (2,359,296 ushort, deform B frag-packed, bf16-hi)
//   owph :   147,456  (  294,912 ushort, offset-conv B frag-packed)
//   xTA  : 2,097,152  (4,194,304 ushort, plane ping)
//   xTB  : 2,097,152  (4,194,304 ushort, plane pong)
// total 5,816,320 floats = 23.3 MB

#define HW 4096

typedef __attribute__((ext_vector_type(8))) __bf16 bf16x8;
typedef __attribute__((ext_vector_type(4))) float f32x4;
typedef __attribute__((ext_vector_type(8))) unsigned short u16x8;

__device__ inline unsigned int f2bf_bits(float f) {
  unsigned int u = __float_as_uint(f);
  return (u + 0x7fffu + ((u >> 16) & 1u)) >> 16;   // RNE to bf16
}
__device__ inline float bf_hi_f(unsigned short h) {
  return __uint_as_float(((unsigned int)h) << 16);
}

// ---------------------------------------------------------------------------
// w[r][o][c][ky][kx] -> frag-packed wph[r][q=72][nt=16][lane=64][j=8] (bf16-hi)
// n = nt*16+(lane&15); kk = q*32+(lane>>4)*8+j; c = kk&255; k = kk>>8.
__global__ __launch_bounds__(256) void wpack_kernel(
    const float* __restrict__ w, unsigned short* __restrict__ wph) {
  const int f = blockIdx.x * 256 + threadIdx.x;   // < 2,359,296
  const int j  = f & 7;
  const int l  = (f >> 3) & 63;
  const int nt = (f >> 9) & 15;
  const int q  = (f >> 13) % 72;
  const int r  = f / 589824;
  const int n  = nt * 16 + (l & 15);
  const int kk = q * 32 + ((l >> 4) << 3) + j;
  const int c  = kk & 255, k = kk >> 8;
  wph[f] = (unsigned short)f2bf_bits(w[((r * 256 + n) * 256 + c) * 9 + k]);
}

// offw[r][18][256][3][3] -> owph[r][q=72][nt=2][lane=64][j=8] (n>=18 -> 0)
__global__ __launch_bounds__(256) void offwpack_kernel(
    const float* __restrict__ offw, unsigned short* __restrict__ owph) {
  const int f = blockIdx.x * 256 + threadIdx.x;   // < 294,912
  const int j  = f & 7;
  const int l  = (f >> 3) & 63;
  const int nt = (f >> 9) & 1;
  const int q  = (f >> 10) % 72;
  const int r  = f / 73728;
  const int n  = nt * 16 + (l & 15);
  const int kk = q * 32 + ((l >> 4) << 3) + j;
  const int c  = kk & 255, k = kk >> 8;
  const float v = (n < 18) ? offw[((r * 18 + n) * 256 + c) * 9 + k] : 0.f;
  owph[f] = (unsigned short)f2bf_bits(v);
}

// ---------------------------------------------------------------------------
// x [4][256][4096] fp32 -> xT [4][4096][256] bf16-hi (transpose + cast)
__global__ __launch_bounds__(256) void xpose_kernel(
    const float* __restrict__ x, unsigned short* __restrict__ xh) {
  const int p0 = blockIdx.x * 64;     // pos tile
  const int c0 = blockIdx.y * 64;     // channel tile
  const int b  = blockIdx.z;
  __shared__ float sT[64][65];
  const int t = threadIdx.x;
  const int pj = t & 63, ci0 = (t >> 6) * 16;
  const float* __restrict__ xb = x + ((size_t)(b * 256 + c0)) * HW + p0;
#pragma unroll
  for (int u = 0; u < 16; ++u)
    sT[ci0 + u][pj] = xb[(size_t)(ci0 + u) * HW + pj];
  __syncthreads();
  const int pr = t >> 2, cs = (t & 3) * 16;
  u16x8 va, vb;
#pragma unroll
  for (int u = 0; u < 8; ++u) va[u] = (unsigned short)f2bf_bits(sT[cs + u][pr]);
#pragma unroll
  for (int u = 0; u < 8; ++u) vb[u] = (unsigned short)f2bf_bits(sT[cs + 8 + u][pr]);
  const size_t o = ((size_t)b * HW + p0 + pr) * 256 + c0 + cs;
  *(u16x8*)(xh + o) = va;
  *(u16x8*)(xh + o + 8) = vb;
}

// ---------------------------------------------------------------------------
// Offset conv, zero-LDS MFMA (r4-proven). block = 32m x 32n, 4 waves.
__global__ __launch_bounds__(256) void offconv_mfma(
    const unsigned short* __restrict__ xh,
    const unsigned short* __restrict__ owh,
    const float* __restrict__ bias, float* __restrict__ offs) {
  const int gid = blockIdx.x;                 // 0..511
  const int b = (gid & 7) >> 1;
  const int idx = ((gid >> 3) << 1) | (gid & 1);   // 0..127
  const int h = idx >> 1, w0 = (idx & 1) << 5;
  const int t = threadIdx.x, lane = t & 63, wv = t >> 6;
  const int frow = lane & 15, fgrp = lane >> 4;
  const int mt = wv & 1, nt = wv >> 1;
  const int m = w0 + mt * 16 + frow;          // w coordinate of A row

  f32x4 acc = {0.f, 0.f, 0.f, 0.f};
  const u16x8 z8 = {};
  const size_t xb = (size_t)b * HW;

  for (int k = 0; k < 9; ++k) {
    const int ky = k / 3 - 1, kx = k % 3 - 1;
    if ((unsigned)(h + ky) >= 64u) continue;  // block-uniform: tap row is 0
    const bool vpx = (unsigned)(m + kx) < 64u;
    const int cpx = (m + kx) < 0 ? 0 : ((m + kx) > 63 ? 63 : (m + kx));
    const size_t abase = (xb + (size_t)((h + ky) * 64 + cpx)) * 256 + fgrp * 8;
#pragma unroll
    for (int cc = 0; cc < 8; ++cc) {
      const int q = k * 8 + cc;
      u16x8 ahr = *(const u16x8*)(xh + abase + cc * 32);
      if (!vpx) ahr = z8;
      const u16x8 bhr = ((const u16x8*)owh)[(q * 2 + nt) * 64 + lane];
      const bf16x8 ah = __builtin_bit_cast(bf16x8, ahr);
      const bf16x8 bh = __builtin_bit_cast(bf16x8, bhr);
      acc = __builtin_amdgcn_mfma_f32_16x16x32_bf16(ah, bh, acc, 0, 0, 0);
    }
  }
  const int oc = nt * 16 + frow;              // C/D: col = lane&15 -> n
  if (oc < 18) {
    const float bv = bias[oc];
    const int wbase = w0 + mt * 16 + fgrp * 4;  // C/D: row = (lane>>4)*4 + r
    float* __restrict__ op = offs + (size_t)(b * 18 + oc) * HW + h * 64 + wbase;
#pragma unroll
    for (int r = 0; r < 4; ++r) op[r] = acc[r] + bv;
  }
}

// ---------------------------------------------------------------------------
// Fused bilinear-sample + bf16 MFMA GEMM + ReLU, software-pipelined with
// LITERAL double-buffer indices (no runtime-indexed register arrays).
// Block: M=64 (full row h), N=128 (half of channels, nh). 4 waves as
// 2m-groups x 2n-groups; per wave 2 m-tiles x 4 n-tiles x 2 products.
__global__ __launch_bounds__(256) void deform_mfma(
    const unsigned short* __restrict__ xh,   // [4][4096][256] bf16-hi plane
    const float* __restrict__ offs,          // [4][18][4096]
    const unsigned short* __restrict__ wph,  // [72][16][64][8] this layer
    unsigned short* __restrict__ yth,        // next plane (layers 0-2)
    float* __restrict__ outf) {              // fp32 NCHW out (layer 3)
  const int gid = blockIdx.x;                  // 0..511
  const int b = (gid & 7) >> 1;                // 2 XCDs per batch image
  const int rh = ((gid >> 3) << 1) | (gid & 1);   // 0..127
  const int h = rh >> 1, nh = rh & 1;
  const int t = threadIdx.x, lane = t & 63, wv = t >> 6;
  const int mw = wv & 1, nw = wv >> 1;
  const int frow = lane & 15, quad = lane >> 4;
  const int sm = t & 63, cg = t >> 6;          // staging: m, channel group

  __shared__ __align__(16) unsigned char s_mem[18432];
  float* s_cw = (float*)s_mem;                 // [9][4][64]
  int*   s_ci = (int*)(s_mem + 9216);          // [9][4][64]
  __shared__ __align__(16) unsigned short sA[2][2][64][40];  // [buf][hi/lo][m][k]

  // phase 0: per (k, m) bilinear setup, m = w coordinate (full row)
  for (int i = t; i < 576; i += 256) {
    const int k = i >> 6, m = i & 63;
    const int ky = k / 3 - 1, kx = k % 3 - 1;
    const int pos = h * 64 + m;
    const float dy = offs[(b * 18 + 2 * k) * HW + pos];
    const float dx = offs[(b * 18 + 2 * k + 1) * HW + pos];
    const float py = (float)(h + ky) + dy;
    const float px = (float)(m + kx) + dx;
    const float y0f = floorf(py), x0f = floorf(px);
    const float wy = py - y0f, wx = px - x0f;
    const int y0 = (int)y0f, x0 = (int)x0f;
#pragma unroll
    for (int j = 0; j < 4; ++j) {
      const int yi = y0 + (j >> 1), xi = x0 + (j & 1);
      const bool v = (yi >= 0) && (yi < 64) && (xi >= 0) && (xi < 64);
      const float wgt = ((j >> 1) ? wy : 1.f - wy) * ((j & 1) ? wx : 1.f - wx);
      s_cw[(k * 4 + j) * 64 + m] = v ? wgt : 0.f;
      const int yc = yi < 0 ? 0 : (yi > 63 ? 63 : yi);
      const int xc = xi < 0 ? 0 : (xi > 63 ? 63 : xi);
      s_ci[(k * 4 + j) * 64 + m] = yc * 64 + xc;
    }
  }
  __syncthreads();

  f32x4 acc[2][4];
#pragma unroll
  for (int mt = 0; mt < 2; ++mt)
#pragma unroll
    for (int nt = 0; nt < 4; ++nt) acc[mt][nt] = (f32x4){0.f, 0.f, 0.f, 0.f};

  const unsigned short* __restrict__ xbh = xh + (size_t)b * HW * 256;
  const u16x8* __restrict__ wp = (const u16x8*)wph;
  const int bfo = nh * 8 + nw * 4;             // B frag n-offset (x64 lanes)

  u16x8 G0[4], G1[4], B0[4], B1[4];
  float cwr[4]; int cir[4];
#pragma unroll
  for (int j = 0; j < 4; ++j) {   // tap 0 staging params
    cwr[j] = s_cw[j * 64 + sm];
    cir[j] = s_ci[j * 64 + sm];
  }
#pragma unroll
  for (int j = 0; j < 4; ++j)     // chunk 0 gather (c0 = cg*8)
    G0[j] = *(const u16x8*)(xbh + (size_t)cir[j] * 256 + cg * 8);
#pragma unroll
  for (int i = 0; i < 4; ++i)     // chunk 0 B frags
    B0[i] = wp[(bfo + i) * 64 + lane];

#define COMBINE_STORE(Gx, buf)                                              \
  {                                                                         \
    float v[8];                                                             \
    _Pragma("unroll") for (int u = 0; u < 8; ++u) {                         \
      float s = cwr[0] * bf_hi_f(Gx[0][u]);                                 \
      s = fmaf(cwr[1], bf_hi_f(Gx[1][u]), s);                               \
      s = fmaf(cwr[2], bf_hi_f(Gx[2][u]), s);                               \
      v[u] = fmaf(cwr[3], bf_hi_f(Gx[3][u]), s);                            \
    }                                                                       \
    u16x8 hv, lv;                                                           \
    _Pragma("unroll") for (int u = 0; u < 8; ++u) {                         \
      const unsigned int hb = f2bf_bits(v[u]);                              \
      hv[u] = (unsigned short)hb;                                           \
      lv[u] = (unsigned short)f2bf_bits(v[u] - __uint_as_float(hb << 16));  \
    }                                                                       \
    *(u16x8*)&sA[buf][0][sm][cg * 8] = hv;                                  \
    *(u16x8*)&sA[buf][1][sm][cg * 8] = lv;                                  \
  }

#define MFMA_BODY(buf, Bx)                                                  \
  {                                                                         \
    bf16x8 ah[2], al[2];                                                    \
    _Pragma("unroll") for (int mt = 0; mt < 2; ++mt) {                      \
      const int row = (mw * 2 + mt) * 16 + frow;                            \
      ah[mt] = __builtin_bit_cast(bf16x8,                                   \
                                  *(const u16x8*)&sA[buf][0][row][quad * 8]); \
      al[mt] = __builtin_bit_cast(bf16x8,                                   \
                                  *(const u16x8*)&sA[buf][1][row][quad * 8]); \
    }                                                                       \
    _Pragma("unroll") for (int nt = 0; nt < 4; ++nt) {                      \
      const bf16x8 bv = __builtin_bit_cast(bf16x8, Bx[nt]);                 \
      _Pragma("unroll") for (int mt = 0; mt < 2; ++mt) {                    \
        acc[mt][nt] = __builtin_amdgcn_mfma_f32_16x16x32_bf16(              \
            ah[mt], bv, acc[mt][nt], 0, 0, 0);                              \
        acc[mt][nt] = __builtin_amdgcn_mfma_f32_16x16x32_bf16(              \
            al[mt], bv, acc[mt][nt], 0, 0, 0);                              \
      }                                                                     \
    }                                                                       \
  }

  for (int it = 0; it < 36; ++it) {
    const int cc0 = it * 2;
    // ---- body A: chunk cc0 (regs G0/B0) -> sA[0]; prefetch cc0+1 -> G1/B1
    COMBINE_STORE(G0, 0)
    __syncthreads();
    {
      const int c0 = ((cc0 + 1) & 7) * 32 + cg * 8;   // same tap (cc0+1 odd)
#pragma unroll
      for (int j = 0; j < 4; ++j)
        G1[j] = *(const u16x8*)(xbh + (size_t)cir[j] * 256 + c0);
#pragma unroll
      for (int i = 0; i < 4; ++i)
        B1[i] = wp[((size_t)(cc0 + 1) * 16 + bfo + i) * 64 + lane];
    }
    MFMA_BODY(0, B0)
    // ---- body B: chunk cc0+1 (regs G1/B1) -> sA[1]; prefetch cc0+2 -> G0/B0
    COMBINE_STORE(G1, 1)
    __syncthreads();
    if (it < 35) {
      const int cc2 = cc0 + 2;
      if ((cc2 & 7) == 0) {                    // new tap (cc2 even only)
        const int k = cc2 >> 3;
#pragma unroll
        for (int j = 0; j < 4; ++j) {
          cwr[j] = s_cw[(k * 4 + j) * 64 + sm];
          cir[j] = s_ci[(k * 4 + j) * 64 + sm];
        }
      }
      const int c0 = (cc2 & 7) * 32 + cg * 8;
#pragma unroll
      for (int j = 0; j < 4; ++j)
        G0[j] = *(const u16x8*)(xbh + (size_t)cir[j] * 256 + c0);
#pragma unroll
      for (int i = 0; i < 4; ++i)
        B0[i] = wp[((size_t)cc2 * 16 + bfo + i) * 64 + lane];
    }
    MFMA_BODY(1, B1)
  }
#undef COMBINE_STORE
#undef MFMA_BODY

  if (outf) {
    // final layer: ReLU + direct fp32 NCHW scatter (float4 per tile-row)
#pragma unroll
    for (int mt = 0; mt < 2; ++mt)
#pragma unroll
      for (int nt = 0; nt < 4; ++nt) {
        const int n = nh * 128 + (nw * 4 + nt) * 16 + frow;
        const int pos = h * 64 + (mw * 2 + mt) * 16 + quad * 4;
        float4 vv;
        vv.x = fmaxf(acc[mt][nt][0], 0.f);
        vv.y = fmaxf(acc[mt][nt][1], 0.f);
        vv.z = fmaxf(acc[mt][nt][2], 0.f);
        vv.w = fmaxf(acc[mt][nt][3], 0.f);
        *(float4*)&outf[(size_t)(b * 256 + n) * HW + pos] = vv;
      }
  } else {
    // layers 0-2: ReLU + bf16-hi transposed plane via per-wave LDS slice
    __syncthreads();   // all K-loop s_mem/sA traffic done before union reuse
    unsigned short* sW = (unsigned short*)s_mem + wv * 2048;  // [32][64]
#pragma unroll
    for (int mt = 0; mt < 2; ++mt)
#pragma unroll
      for (int nt = 0; nt < 4; ++nt)
#pragma unroll
        for (int r = 0; r < 4; ++r)
          sW[(mt * 16 + quad * 4 + r) * 64 + nt * 16 + frow] =
              (unsigned short)f2bf_bits(fmaxf(acc[mt][nt][r], 0.f));
    __syncthreads();
    const int lm = lane & 31, cg2 = lane >> 5;
    const int pos = h * 64 + mw * 32 + lm;
    unsigned short* __restrict__ yp =
        yth + ((size_t)b * HW + pos) * 256 + nh * 128 + nw * 64 + cg2 * 32;
#pragma unroll
    for (int g = 0; g < 4; ++g)
      *(u16x8*)(yp + g * 8) = *(const u16x8*)&sW[lm * 64 + cg2 * 32 + g * 8];
  }
}

extern "C" void kernel_launch(void* const* d_in, const int* in_sizes, int n_in,
                              void* d_out, int out_size, void* d_ws, size_t ws_size,
                              hipStream_t stream) {
  const float* x0   = (const float*)d_in[0];  // [4][256][64][64]
  const float* offw = (const float*)d_in[1];  // [4][18][256][3][3]
  const float* offb = (const float*)d_in[2];  // [4][18]
  const float* w    = (const float*)d_in[3];  // [4][256][256][3][3]
  float* out = (float*)d_out;                 // [4][256][64][64]
  float* ws  = (float*)d_ws;

  float* offs = ws;                                     //   294,912 floats
  unsigned short* wph  = (unsigned short*)(ws + 294912);    // 2,359,296 ushort
  unsigned short* owph = wph + 2359296;                     //   294,912 ushort
  unsigned short* xTA  = owph + 294912;                     // 4,194,304 ushort
  unsigned short* xTB  = xTA + 4194304;                     // 4,194,304 ushort

  wpack_kernel<<<9216, 256, 0, stream>>>(w, wph);
  offwpack_kernel<<<1152, 256, 0, stream>>>(offw, owph);
  xpose_kernel<<<dim3(64, 4, 4), 256, 0, stream>>>(x0, xTA);

  unsigned short* pin = xTA;
  unsigned short* pout = xTB;
  for (int r = 0; r < 4; ++r) {
    offconv_mfma<<<512, 256, 0, stream>>>(pin, owph + r * 73728,
                                          offb + r * 18, offs);
    deform_mfma<<<512, 256, 0, stream>>>(pin, offs,
                                         wph + (size_t)r * 589824,
                                         (r < 3) ? pout : nullptr,
                                         (r < 3) ? nullptr : out);
    unsigned short* tmp = pin; pin = pout; pout = tmp;
  }
}